// Round 5
// baseline (1237.343 us; speedup 1.0000x reference)
//
#include <hip/hip_runtime.h>
#include <cstddef>

typedef short bf16x8 __attribute__((ext_vector_type(8)));   // 8 bf16 in 4 VGPRs
typedef float f32x4  __attribute__((ext_vector_type(4)));
typedef unsigned short u16x8 __attribute__((ext_vector_type(8)));

namespace {
constexpr float QSCALE = 0.17677669529663687f;  // 32^-0.5, folded into wq/bq at prep

// ---- workspace layout (bytes) ----
constexpr size_t BQKV_OFF = 0;                         // ushort[576][384]  B_T for qkv, [wh|wl] split
constexpr size_t WOUT_OFF = 576 * 384 * 2;             // ushort[192][384]  B_T for wout
constexpr size_t BQG_OFF  = WOUT_OFF + 192 * 384 * 2;  // float[576] head-grouped qkv bias
constexpr size_t QG_OFF   = BQG_OFF + 576 * 4;         // ushort[11160][72][32]  q  (scaled, bf16)
constexpr size_t KG_OFF   = QG_OFF + (size_t)11160 * 2304 * 2;  // ushort[11160][72][32]  k
constexpr size_t VG_OFF   = KG_OFF + (size_t)11160 * 2304 * 2;  // ushort[11160][72][32]  v (row-major)
// total ~148 MiB — verified OK in rounds 3/4. xs (split x) lives in d_out, not ws.
}

__device__ __forceinline__ unsigned short f2bf(float f) {
  unsigned int u = __builtin_bit_cast(unsigned int, f);
  return (unsigned short)((u + 0x7FFFu + ((u >> 16) & 1u)) >> 16);   // RNE
}
__device__ __forceinline__ float bf2f(unsigned short h) {
  unsigned int u = ((unsigned int)h) << 16;
  return __builtin_bit_cast(float, u);
}
__device__ __forceinline__ int moffv(int i) { return (i < 4) ? i * 16 : 56; }  // m-tiles {0,16,32,48,56}

// ---------------- prep: weights -> split-bf16 B_T layouts in ws ----------------
__global__ __launch_bounds__(256)
void prep_kernel(const float* __restrict__ wqkv, const float* __restrict__ bqkv,
                 const float* __restrict__ wout, unsigned char* __restrict__ ws) {
  int t = blockIdx.x * 256 + threadIdx.x;
  unsigned short* Bq = (unsigned short*)(ws + BQKV_OFF);
  unsigned short* Bo = (unsigned short*)(ws + WOUT_OFF);
  float* bqg = (float*)(ws + BQG_OFF);
  if (t < 576 * 384) {
    int n = t / 384, kk = t % 384;
    int ksrc = kk % 192, part = kk / 192;
    int h = n / 96, r96 = n % 96, kind = r96 / 32, d = r96 % 32;
    float w = wqkv[(size_t)ksrc * 576 + kind * 192 + h * 32 + d];
    if (kind == 0) w *= QSCALE;
    unsigned short hi = f2bf(w);
    Bq[t] = part ? f2bf(w - bf2f(hi)) : hi;
  } else if (t < 576 * 384 + 192 * 384) {
    int t2 = t - 576 * 384;
    int n = t2 / 384, kk = t2 % 384, ksrc = kk % 192, part = kk / 192;
    float w = wout[(size_t)ksrc * 192 + n];
    unsigned short hi = f2bf(w);
    Bo[t2] = part ? f2bf(w - bf2f(hi)) : hi;
  } else if (t < 576 * 384 + 192 * 384 + 576) {
    int n = t - (576 * 384 + 192 * 384);
    int h = n / 96, r96 = n % 96, kind = r96 / 32, d = r96 % 32;
    float b = bqkv[kind * 192 + h * 32 + d];
    if (kind == 0) b *= QSCALE;
    bqg[n] = b;
  }
}

// ---------------- xsplit: x(f32) -> split-bf16 planes [nw*72][hi 0-191 | lo 192-383] in d_out ----------------
__global__ __launch_bounds__(256)
void xsplit_kernel(const float* __restrict__ x, unsigned short* __restrict__ xs, int njobs) {
  int i = blockIdx.x * 256 + threadIdx.x;
  if (i >= njobs) return;
  int r = i / 48, c4 = i % 48;
  float4 v = *(const float4*)(x + (size_t)r * 192 + c4 * 4);
  unsigned short h0 = f2bf(v.x), h1 = f2bf(v.y), h2 = f2bf(v.z), h3 = f2bf(v.w);
  ushort4 hv; hv.x = h0; hv.y = h1; hv.z = h2; hv.w = h3;
  ushort4 lv;
  lv.x = f2bf(v.x - bf2f(h0)); lv.y = f2bf(v.y - bf2f(h1));
  lv.z = f2bf(v.z - bf2f(h2)); lv.w = f2bf(v.w - bf2f(h3));
  *(ushort4*)(xs + (size_t)r * 384 + c4 * 4) = hv;
  *(ushort4*)(xs + (size_t)r * 384 + 192 + c4 * 4) = lv;
}

// One (head,kind) pair-job: NM m-tiles x 2 n-tiles, K=192 x 3 split-terms, A/B from L2.
// Epilogue: transpose C-fragments through wave-private LDS -> full 64B-line global writes.
template<int NM>
__device__ __forceinline__ void qkv_job(
    const unsigned short* __restrict__ xsw, const unsigned short* __restrict__ Bq,
    const float* __restrict__ bqg, unsigned short* ep,
    unsigned short* __restrict__ qg, unsigned short* __restrict__ kg,
    unsigned short* __restrict__ vg,
    int w, int p, int m0idx, int lanen, int quad, int lane) {
  const unsigned short* b0p = Bq + (size_t)(p * 32 + lanen) * 384 + quad * 8;
  const unsigned short* arow[NM];
  #pragma unroll
  for (int mi = 0; mi < NM; ++mi)
    arow[mi] = xsw + (moffv(m0idx + mi) + lanen) * 384 + quad * 8;

  f32x4 acc0[NM], acc1[NM];
  #pragma unroll
  for (int mi = 0; mi < NM; ++mi) {
    acc0[mi] = (f32x4){0.f, 0.f, 0.f, 0.f};
    acc1[mi] = (f32x4){0.f, 0.f, 0.f, 0.f};
  }
  #pragma unroll 1
  for (int reg = 0; reg < 3; ++reg) {          // xh*wh, xh*wl, xl*wh
    const int ab = (reg == 2) ? 192 : 0;
    const int bb = (reg == 1) ? 192 : 0;
    #pragma unroll
    for (int s = 0; s < 6; ++s) {
      bf16x8 b0 = *(const bf16x8*)(b0p + bb + 32 * s);
      bf16x8 b1 = *(const bf16x8*)(b0p + 6144 + bb + 32 * s);   // +16 rows
      #pragma unroll
      for (int mi = 0; mi < NM; ++mi) {
        bf16x8 a = *(const bf16x8*)(arow[mi] + ab + 32 * s);
        acc0[mi] = __builtin_amdgcn_mfma_f32_16x16x32_bf16(a, b0, acc0[mi], 0, 0, 0);
        acc1[mi] = __builtin_amdgcn_mfma_f32_16x16x32_bf16(a, b1, acc1[mi], 0, 0, 0);
      }
    }
  }
  const int h = p / 3, kind = p - h * 3;
  const float bias0 = bqg[p * 32 + lanen], bias1 = bqg[p * 32 + 16 + lanen];
  unsigned short* dstA = ((kind == 0) ? qg : (kind == 1) ? kg : vg) + (size_t)(w * 6 + h) * 2304;
  const int row = lane >> 2, cq = lane & 3;
  #pragma unroll
  for (int mi = 0; mi < NM; ++mi) {
    const int mo = moffv(m0idx + mi);
    #pragma unroll
    for (int r = 0; r < 4; ++r) {              // stage [16][32(+8 pad)] in wave-private LDS
      ep[(quad * 4 + r) * 40 + lanen]      = f2bf(acc0[mi][r] + bias0);
      ep[(quad * 4 + r) * 40 + 16 + lanen] = f2bf(acc1[mi][r] + bias1);
    }
    // readback + coalesced store: wave writes 16 rows x 64B = 1024B contiguous
    uint4 vv = *(const uint4*)(ep + row * 40 + cq * 8);
    *(uint4*)(dstA + (size_t)(mo + row) * 32 + cq * 8) = vv;
  }
}

// ---------------- kernel A: QKV GEMM, no barriers, 8 waves/SIMD ----------------
__global__ __launch_bounds__(512, 8)   // force VGPR<=64 -> 32 waves/CU (LDS only 10KB)
void qkv_kernel(const unsigned short* __restrict__ xs, unsigned char* __restrict__ ws) {
  __shared__ __attribute__((aligned(16))) unsigned short EP[8 * 640];  // 8 waves x [16][40]
  const int w = blockIdx.x, tid = threadIdx.x;
  const int lane = tid & 63, ty = tid >> 6;
  const int lanen = lane & 15, quad = lane >> 4;
  const int mg = ty >> 2, col = ty & 3;
  const unsigned short* xsw = xs + (size_t)w * (72 * 384);
  const unsigned short* Bq = (const unsigned short*)(ws + BQKV_OFF);
  const float* bqg = (const float*)(ws + BQG_OFF);
  unsigned short* qg = (unsigned short*)(ws + QG_OFF);
  unsigned short* kg = (unsigned short*)(ws + KG_OFF);
  unsigned short* vg = (unsigned short*)(ws + VG_OFF);
  unsigned short* ep = EP + ty * 640;

  if (mg == 0) {                               // m-tiles {0,16,32}
    #pragma unroll 1
    for (int p = col; p < 18; p += 4)
      qkv_job<3>(xsw, Bq, bqg, ep, qg, kg, vg, w, p, 0, lanen, quad, lane);
  } else {                                     // m-tiles {48,56}
    #pragma unroll 1
    for (int p = col; p < 18; p += 4)
      qkv_job<2>(xsw, Bq, bqg, ep, qg, kg, vg, w, p, 3, lanen, quad, lane);
  }
}

// ---------------- kernel B: attention per (window, head) -> split-po planes in d_out ----------------
__global__ __launch_bounds__(320, 5)
void attn_core(const float* __restrict__ mask, const float* __restrict__ btab,
               const unsigned char* __restrict__ ws, float* __restrict__ out) {
  __shared__ __attribute__((aligned(16))) unsigned short V2[32 * 104];      // v^T, tokens padded (zeros)
  __shared__ __attribute__((aligned(16))) unsigned short PB[5 * 16 * 104];  // wave-private P bufs
  const int b = blockIdx.x, w = b / 6, hh = b - w * 6;
  const int tid = threadIdx.x, lane = tid & 63, ty = tid >> 6;
  const int lanen = lane & 15, quad = lane >> 4;
  const int mrow = w % 30, tlat = w % 31, w31 = w / 31;
  const unsigned short* qg = (const unsigned short*)(ws + QG_OFF) + (size_t)b * 2304;
  const unsigned short* kg = (const unsigned short*)(ws + KG_OFF) + (size_t)b * 2304;
  const unsigned short* vg = (const unsigned short*)(ws + VG_OFF) + (size_t)b * 2304;
  const float* maskw = mask + (size_t)mrow * 5184;

  const int mo = moffv(ty);                           // one m-strip per wave

  // ---- A) issue ALL global loads up front: q-frag, 5 k-tiles, 20 bias+mask gathers ----
  bf16x8 afr = *(const bf16x8*)(qg + (mo + lanen) * 32 + quad * 8);
  bf16x8 kfr[5];
  #pragma unroll
  for (int t = 0; t < 5; ++t) {
    int no = (t < 4) ? t * 16 : 64;                   // tail rows 72-79 read in-ws garbage, masked below
    kfr[t] = *(const bf16x8*)(kg + (no + lanen) * 32 + quad * 8);
  }
  float pre[5][4];                                    // bias+mask, folded before MFMA results arrive
  #pragma unroll
  for (int t = 0; t < 5; ++t) {
    int ct = ((t < 4) ? t * 16 : 64) + lanen;
    #pragma unroll
    for (int r = 0; r < 4; ++r) {
      if (ct < 72) {
        int m = mo + quad * 4 + r;
        unsigned int e = (unsigned)(m % 6); e = e ? 6u - e : 0u;
        unsigned int T = 864u * e + 60u * (unsigned)ct + (unsigned)w31;
        if (T >= 5184u) T -= 5184u;
        unsigned int p1 = T / 72u, p2 = T - 72u * p1;
        unsigned int i1 = p1 / 12u, j1 = p1 - 12u * i1;
        unsigned int i2 = p2 / 12u, j2 = p2 - 12u * i2;
        int rowb = (int)((i1 + 6u * i2) * 23u + j1) - (int)j2 + 11;
        pre[t][r] = btab[(size_t)rowb * 186 + tlat * 6 + hh] + maskw[m * 72 + ct];
      } else pre[t][r] = 0.f;
    }
  }

  // ---- B) stage V2 = v^T (transpose of row-major vg) + zero pads; PB pads (wave-private) ----
  for (int i = tid; i < 576; i += 320) {              // 72 tokens x 8 col-quads
    int t = i >> 3, c = i & 7;
    ushort4 vv = *(const ushort4*)(vg + t * 32 + c * 4);
    V2[(c * 4 + 0) * 104 + t] = vv.x; V2[(c * 4 + 1) * 104 + t] = vv.y;
    V2[(c * 4 + 2) * 104 + t] = vv.z; V2[(c * 4 + 3) * 104 + t] = vv.w;
  }
  for (int i = tid; i < 1024; i += 320) {             // zero token-pads 72..103
    int d = i >> 5, j = i & 31;
    V2[d * 104 + 72 + j] = 0;
  }
  {
    int wv = tid >> 6, rr = (tid >> 2) & 15, c = tid & 3;   // wave-private pad zero (320 jobs)
    *(uint4*)(PB + wv * 1664 + rr * 104 + 72 + c * 8) = make_uint4(0u, 0u, 0u, 0u);
  }

  // ---- C) QK MFMA (register-only inputs) ----
  f32x4 s[5];
  #pragma unroll
  for (int t = 0; t < 5; ++t) {
    s[t] = (f32x4){0.f, 0.f, 0.f, 0.f};
    s[t] = __builtin_amdgcn_mfma_f32_16x16x32_bf16(afr, kfr[t], s[t], 0, 0, 0);
  }

  // ---- D) softmax in C-layout registers; P -> wave-private LDS ----
  unsigned short* pb = PB + ty * 1664;
  float lg[5][4];
  #pragma unroll
  for (int t = 0; t < 5; ++t) {
    int ct = ((t < 4) ? t * 16 : 64) + lanen;
    #pragma unroll
    for (int r = 0; r < 4; ++r)
      lg[t][r] = (ct < 72) ? (s[t][r] + pre[t][r]) : -1e30f;  // kill tail garbage (incl. NaN)
  }
  #pragma unroll
  for (int r = 0; r < 4; ++r) {
    float mx = fmaxf(fmaxf(fmaxf(lg[0][r], lg[1][r]), fmaxf(lg[2][r], lg[3][r])), lg[4][r]);
    #pragma unroll
    for (int o = 8; o > 0; o >>= 1) mx = fmaxf(mx, __shfl_xor(mx, o));
    float sum = 0.f;
    #pragma unroll
    for (int t = 0; t < 5; ++t) { lg[t][r] = __expf(lg[t][r] - mx); sum += lg[t][r]; }
    #pragma unroll
    for (int o = 8; o > 0; o >>= 1) sum += __shfl_xor(sum, o);
    float inv = 1.0f / sum;
    #pragma unroll
    for (int t = 0; t < 5; ++t) {
      int ct = ((t < 4) ? t * 16 : 64) + lanen;
      if (ct < 72) pb[(quad * 4 + r) * 104 + ct] = f2bf(lg[t][r] * inv);
    }
  }

  __syncthreads();                                    // V2 ready (PB is wave-private)

  // ---- E) O = P V ----
  f32x4 o2[2];
  o2[0] = (f32x4){0.f, 0.f, 0.f, 0.f}; o2[1] = (f32x4){0.f, 0.f, 0.f, 0.f};
  #pragma unroll
  for (int ks = 0; ks < 3; ++ks) {
    bf16x8 pfr = *(const bf16x8*)(pb + lanen * 104 + ks * 32 + quad * 8);
    #pragma unroll
    for (int n2 = 0; n2 < 2; ++n2) {
      bf16x8 vfr = *(const bf16x8*)(V2 + (n2 * 16 + lanen) * 104 + ks * 32 + quad * 8);
      o2[n2] = __builtin_amdgcn_mfma_f32_16x16x32_bf16(pfr, vfr, o2[n2], 0, 0, 0);
    }
  }

  // ---- F) po -> split bf16 planes [row][hi 0-191 | lo 192-383] via wave-private transpose ----
  float* pbf = (float*)(pb);                          // [16][36] f32 (2304B < 3328B slice)
  #pragma unroll
  for (int n2 = 0; n2 < 2; ++n2)
    #pragma unroll
    for (int r = 0; r < 4; ++r)
      pbf[(quad * 4 + r) * 36 + n2 * 16 + lanen] = o2[n2][r];
  {
    const int row = lane >> 2, c8 = lane & 3;
    const float* src = pbf + row * 36 + c8 * 8;
    u16x8 hv, lv;
    #pragma unroll
    for (int j = 0; j < 8; ++j) {
      float v = src[j];
      unsigned short hi = f2bf(v);
      hv[j] = hi; lv[j] = f2bf(v - bf2f(hi));
    }
    unsigned short* pov = (unsigned short*)out + ((size_t)w * 72 + mo + row) * 384 + hh * 32 + c8 * 8;
    *(u16x8*)pov = hv;                 // full 64B lines per 4 lanes
    *(u16x8*)(pov + 192) = lv;
  }
}

// ---------------- kernel C: out = po @ w_out + b_out, 24-row blocks, in-place ----------------
__global__ __launch_bounds__(256, 8)   // 18.8KB LDS + <=64 VGPR -> 8 blocks/CU = 8 waves/SIMD
void outproj_kernel(const unsigned char* __restrict__ ws, const float* __restrict__ bout,
                    float* __restrict__ out) {
  __shared__ __attribute__((aligned(16))) unsigned short Ax[24 * 392];
  const int blk = blockIdx.x, w = blk / 3, seg = blk % 3;
  const int tid = threadIdx.x, lane = tid & 63, ty = tid >> 6;
  const int lanen = lane & 15, quad = lane >> 4;
  const unsigned short* Bo = (const unsigned short*)(ws + WOUT_OFF);
  const size_t rowbase = (size_t)w * 72 + seg * 24;
  const unsigned short* pov = (const unsigned short*)out + rowbase * 384;
  float* rows = out + rowbase * 192;

  for (int i = tid; i < 1152; i += 256) {    // raw copy: split-po -> LDS
    int r = i / 48, c8 = i % 48;
    *(uint4*)(Ax + r * 392 + c8 * 8) = *(const uint4*)(pov + r * 384 + c8 * 8);
  }
  __syncthreads();                           // after this, in-place overwrite is safe

  const int ngb = ty * 3;                    // 4 waves x 3 n-tiles; m-tiles {0,8}
  const unsigned short* a0p = Ax + lanen * 392 + quad * 8;
  const unsigned short* a1p = Ax + (8 + lanen) * 392 + quad * 8;
  const unsigned short* b0p = Bo + (size_t)(ngb * 16 + lanen) * 384 + quad * 8;
  f32x4 acc[3][2];
  #pragma unroll
  for (int nt = 0; nt < 3; ++nt) {
    acc[nt][0] = (f32x4){0.f, 0.f, 0.f, 0.f};
    acc[nt][1] = (f32x4){0.f, 0.f, 0.f, 0.f};
  }
  #pragma unroll 1
  for (int reg = 0; reg < 3; ++reg) {
    const int ab = (reg == 2) ? 192 : 0;
    const int bb = (reg == 1) ? 192 : 0;
    #pragma unroll
    for (int s = 0; s < 6; ++s) {
      bf16x8 a0 = *(const bf16x8*)(a0p + ab + 32 * s);
      bf16x8 a1 = *(const bf16x8*)(a1p + ab + 32 * s);
      #pragma unroll
      for (int nt = 0; nt < 3; ++nt) {
        bf16x8 bfr = *(const bf16x8*)(b0p + (size_t)nt * 6144 + bb + 32 * s);
        acc[nt][0] = __builtin_amdgcn_mfma_f32_16x16x32_bf16(a0, bfr, acc[nt][0], 0, 0, 0);
        acc[nt][1] = __builtin_amdgcn_mfma_f32_16x16x32_bf16(a1, bfr, acc[nt][1], 0, 0, 0);
      }
    }
  }
  #pragma unroll 1
  for (int nt = 0; nt < 3; ++nt) {
    const int n16 = (ngb + nt) * 16;
    const float bias = bout[n16 + lanen];
    #pragma unroll
    for (int mi = 0; mi < 2; ++mi)
      #pragma unroll
      for (int r = 0; r < 4; ++r)
        rows[(size_t)(mi * 8 + quad * 4 + r) * 192 + n16 + lanen] = acc[nt][mi][r] + bias;
  }
}

extern "C" void kernel_launch(void* const* d_in, const int* in_sizes, int n_in,
                              void* d_out, int out_size, void* d_ws, size_t ws_size,
                              hipStream_t stream) {
  const float* x    = (const float*)d_in[0];
  const float* mask = (const float*)d_in[1];
  const float* wqkv = (const float*)d_in[2];
  const float* bqkv = (const float*)d_in[3];
  const float* wout = (const float*)d_in[4];
  const float* bout = (const float*)d_in[5];
  const float* btab = (const float*)d_in[6];
  float* out = (float*)d_out;
  unsigned char* ws = (unsigned char*)d_ws;
  const int nwindows = in_sizes[0] / (72 * 192);   // 1860
  const int xsjobs = nwindows * 3456;

  // xs (split x) lives in d_out: consumed by qkv_kernel, then overwritten by attn_core (split-po),
  // then overwritten in-place by outproj_kernel (final f32). All stream-ordered.
  xsplit_kernel<<<dim3((xsjobs + 255) / 256), dim3(256), 0, stream>>>(x, (unsigned short*)out, xsjobs);
  prep_kernel<<<dim3(1155), dim3(256), 0, stream>>>(wqkv, bqkv, wout, ws);
  qkv_kernel<<<dim3(nwindows), dim3(512), 0, stream>>>((const unsigned short*)out, ws);
  attn_core<<<dim3(nwindows * 6), dim3(320), 0, stream>>>(mask, btab, ws, out);
  outproj_kernel<<<dim3(nwindows * 3), dim3(256), 0, stream>>>(ws, bout, out);
}